// Round 1
// baseline (73.115 us; speedup 1.0000x reference)
//
#include <hip/hip_runtime.h>
#include <hip/hip_bf16.h>
#include <math.h>

// Problem constants (from reference file)
#define D_IN  128
#define NH    8
#define F_OUT 32
#define HID   256
#define D_EMB 64
#define CAP   1024   // max matched edges we track (expected ~32; Poisson tail -> 1024 is absurdly safe)

__global__ void zero_count(int* c) { *c = 0; }

__global__ __launch_bounds__(256) void scan_edges(
    const int* __restrict__ trg, const int* __restrict__ src,
    const int* __restrict__ bins, const int* __restrict__ li_p,
    const int* __restrict__ ld_p, int nE,
    int* __restrict__ count, int* __restrict__ m_src,
    int* __restrict__ m_trg, int* __restrict__ m_bin) {
  const int li = li_p[0], ld = ld_p[0];
  const int gid = blockIdx.x * blockDim.x + threadIdx.x;
  const int stride = gridDim.x * blockDim.x;
  const int nE4 = nE >> 2;
  const int4* t4 = (const int4*)trg;
  for (int e4 = gid; e4 < nE4; e4 += stride) {
    int4 t = t4[e4];
    int ev[4] = {t.x, t.y, t.z, t.w};
#pragma unroll
    for (int k = 0; k < 4; ++k) {
      int tv = ev[k];
      if (tv == li || tv == ld) {
        int e = e4 * 4 + k;
        int pos = atomicAdd(count, 1);
        if (pos < CAP) { m_src[pos] = src[e]; m_trg[pos] = tv; m_bin[pos] = bins[e]; }
      }
    }
  }
  if (gid == 0) {  // tail (nE not divisible by 4)
    for (int e = nE4 * 4; e < nE; ++e) {
      int tv = trg[e];
      if (tv == li || tv == ld) {
        int pos = atomicAdd(count, 1);
        if (pos < CAP) { m_src[pos] = src[e]; m_trg[pos] = tv; m_bin[pos] = bins[e]; }
      }
    }
  }
}

__global__ __launch_bounds__(256) void gat_head(
    const float* __restrict__ nf,        // N x 128
    const float* __restrict__ ms,        // 256
    const int* __restrict__ li_p, const int* __restrict__ ld_p, const int* __restrict__ dist_p,
    const float* __restrict__ Wproj,     // 256 x 128
    const float* __restrict__ a_src,     // 8 x 32
    const float* __restrict__ a_trg,     // 8 x 32
    const float* __restrict__ Wms,       // 8 x 256
    const float* __restrict__ demb_g,    // 200 x 64
    const float* __restrict__ Wdist,     // 8 x 64
    const float* __restrict__ Wskip,     // 256 x 128
    const float* __restrict__ gbias,     // 32
    const float* __restrict__ demb_h,    // 200 x 64
    const float* __restrict__ W1,        // 256 x 384
    const float* __restrict__ b1,        // 256
    const float* __restrict__ W2,        // 1 x 256
    const float* __restrict__ b2,        // 1
    const int* __restrict__ count,
    const int* __restrict__ m_src, const int* __restrict__ m_trg, const int* __restrict__ m_bin,
    float* __restrict__ out) {

  __shared__ float sm_ms[HID];             // moving_state
  __shared__ float sm_vsrc[NH * D_IN];     // a_src @ Wproj_h  (per head, 128-dim)
  __shared__ float sm_vtrg[NH * D_IN];     // a_trg @ Wproj_h
  __shared__ float sm_nf[2][D_IN];         // node_features[li], [ld]
  __shared__ float sm_sms[NH];             // Wms @ moving_state
  __shared__ float sm_strg[2][NH];         // s_trg for li/ld
  __shared__ float sm_den[2][NH];          // softmax denominators
  __shared__ float sm_sc[CAP * NH];        // exp(leaky_relu(score)) per (edge, head)  32KB
  __shared__ float sm_agg[2 * NH * D_IN];  // sum_e attn * nf[src]   8KB
  __shared__ float sm_whf[2 * NH * F_OUT]; // per-head (proj-agg + skip)
  __shared__ float sm_emb[2 * F_OUT];      // node_emb[li], node_emb[ld]
  __shared__ float sm_feat[HID + 2 * F_OUT + D_EMB]; // 384
  __shared__ float sm_red[4];

  const int tid = threadIdx.x;
  const int li = li_p[0], ld = ld_p[0], dist = dist_p[0];
  int cnt = *count; if (cnt > CAP) cnt = CAP;

  // --- stage inputs ---
  for (int j = tid; j < HID; j += 256) sm_ms[j] = ms[j];
  for (int j = tid; j < D_IN; j += 256) {
    sm_nf[0][j] = nf[(size_t)li * D_IN + j];
    sm_nf[1][j] = nf[(size_t)ld * D_IN + j];
  }
  // v_src[h,d] = sum_f a_src[h,f]*Wproj[h*F+f,d]  (so s_src[n,h] = nf[n] . v_src[h])
  for (int idx = tid; idx < NH * D_IN; idx += 256) {
    int h = idx >> 7, d = idx & 127;
    float vs = 0.f, vt = 0.f;
    for (int f = 0; f < F_OUT; ++f) {
      float w = Wproj[(h * F_OUT + f) * D_IN + d];
      vs = fmaf(a_src[h * F_OUT + f], w, vs);
      vt = fmaf(a_trg[h * F_OUT + f], w, vt);
    }
    sm_vsrc[idx] = vs; sm_vtrg[idx] = vt;
  }
  if (tid < NH) {  // s_ms[h] = Wms[h] . moving_state
    float s = 0.f;
    for (int j = 0; j < HID; ++j) s = fmaf(Wms[tid * HID + j], ms[j], s);
    sm_sms[tid] = s;
  }
  __syncthreads();

  if (tid < 2 * NH) {  // s_trg for li/ld
    int t = tid / NH, h = tid % NH;
    float s = 0.f;
    for (int d = 0; d < D_IN; ++d) s = fmaf(sm_nf[t][d], sm_vtrg[h * D_IN + d], s);
    sm_strg[t][h] = s;
  }
  __syncthreads();

  // --- per-(edge,head) scores: exp(leaky_relu(s_src + s_trg + s_ms + e_score))
  // Global max of reference cancels in attn = exp_s/denom; scores are O(10) so raw exp is safe.
  for (int idx = tid; idx < cnt * NH; idx += 256) {
    int i = idx / NH, h = idx % NH;
    int sv = m_src[i], bv = m_bin[i], tv = m_trg[i];
    const float* nfr = nf + (size_t)sv * D_IN;
    float ssrc = 0.f;
    for (int d = 0; d < D_IN; ++d) ssrc = fmaf(nfr[d], sm_vsrc[h * D_IN + d], ssrc);
    float esc = 0.f;
    const float* de = demb_g + bv * D_EMB;
    for (int d = 0; d < D_EMB; ++d) esc = fmaf(de[d], Wdist[h * D_EMB + d], esc);
    int t = (tv == li) ? 0 : 1;
    float sc = ssrc + sm_strg[t][h] + sm_sms[h] + esc;
    sc = sc > 0.f ? sc : 0.2f * sc;       // leaky_relu(x, 0.2)
    sm_sc[i * NH + h] = expf(sc);
  }
  __syncthreads();

  if (tid < 2 * NH) {  // denominators
    int t = tid / NH, h = tid % NH;
    int tv = t ? ld : li;
    float ds = 0.f;
    for (int i = 0; i < cnt; ++i) if (m_trg[i] == tv) ds += sm_sc[i * NH + h];
    sm_den[t][h] = ds + 1e-16f;
  }
  __syncthreads();

  // agg_nf[t,h,d] = sum_e attn[e,h]*nf[src_e,d]  (linearity: proj after aggregation)
  for (int idx = tid; idx < 2 * NH * D_IN; idx += 256) {
    int t = idx / (NH * D_IN), h = (idx / D_IN) % NH, d = idx & 127;
    int tv = t ? ld : li;
    float acc = 0.f;
    for (int i = 0; i < cnt; ++i)
      if (m_trg[i] == tv) acc = fmaf(sm_sc[i * NH + h], nf[(size_t)m_src[i] * D_IN + d], acc);
    sm_agg[idx] = acc / sm_den[t][h];
  }
  __syncthreads();

  // per-(t,h,f): agg . Wproj_row + nf[t] . Wskip_row
  for (int idx = tid; idx < 2 * NH * F_OUT; idx += 256) {
    int t = idx / (NH * F_OUT), h = (idx / F_OUT) % NH, f = idx % F_OUT;
    const float* wp = Wproj + (h * F_OUT + f) * D_IN;
    const float* wk = Wskip + (h * F_OUT + f) * D_IN;
    const float* ag = sm_agg + (t * NH + h) * D_IN;
    float acc = 0.f;
    for (int d = 0; d < D_IN; ++d) acc = fmaf(ag[d], wp[d], fmaf(sm_nf[t][d], wk[d], acc));
    sm_whf[idx] = acc;
  }
  __syncthreads();

  if (tid < 2 * F_OUT) {  // head-mean + bias + ELU
    int t = tid / F_OUT, f = tid % F_OUT;
    float s = 0.f;
    for (int h = 0; h < NH; ++h) s += sm_whf[(t * NH + h) * F_OUT + f];
    s = s * (1.0f / NH) + gbias[f];
    sm_emb[t * F_OUT + f] = s > 0.f ? s : expm1f(s);
  }
  __syncthreads();

  // --- MLP head ---
  for (int j = tid; j < HID; j += 256) sm_feat[j] = sm_ms[j];
  if (tid < 2 * F_OUT) sm_feat[HID + tid] = sm_emb[tid];
  if (tid < D_EMB) sm_feat[HID + 2 * F_OUT + tid] = demb_h[dist * D_EMB + tid];
  __syncthreads();

  const int FDIM = HID + 2 * F_OUT + D_EMB;  // 384
  float h1 = 0.f;
  const float* w1r = W1 + tid * FDIM;
  for (int j = 0; j < FDIM; ++j) h1 = fmaf(w1r[j], sm_feat[j], h1);
  h1 += b1[tid];
  h1 = fmaxf(h1, 0.f);
  float contrib = W2[tid] * h1;
  for (int off = 32; off > 0; off >>= 1) contrib += __shfl_down(contrib, off);
  if ((tid & 63) == 0) sm_red[tid >> 6] = contrib;
  __syncthreads();
  if (tid == 0) out[0] = sm_red[0] + sm_red[1] + sm_red[2] + sm_red[3] + b2[0];
}

extern "C" void kernel_launch(void* const* d_in, const int* in_sizes, int n_in,
                              void* d_out, int out_size, void* d_ws, size_t ws_size,
                              hipStream_t stream) {
  const float* nf     = (const float*)d_in[0];
  const int*   esrc   = (const int*)d_in[1];
  const int*   etrg   = (const int*)d_in[2];
  const int*   ebin   = (const int*)d_in[3];
  const float* ms     = (const float*)d_in[4];
  const int*   li_p   = (const int*)d_in[5];
  const int*   ld_p   = (const int*)d_in[6];
  const int*   dist_p = (const int*)d_in[7];
  const float* Wproj  = (const float*)d_in[8];
  const float* a_src  = (const float*)d_in[9];
  const float* a_trg  = (const float*)d_in[10];
  const float* Wms    = (const float*)d_in[11];
  const float* demb_g = (const float*)d_in[12];
  const float* Wdist  = (const float*)d_in[13];
  const float* Wskip  = (const float*)d_in[14];
  const float* gbias  = (const float*)d_in[15];
  const float* demb_h = (const float*)d_in[16];
  const float* W1     = (const float*)d_in[17];
  const float* b1     = (const float*)d_in[18];
  const float* W2     = (const float*)d_in[19];
  const float* b2     = (const float*)d_in[20];
  const int nE = in_sizes[1];

  int* ws_i  = (int*)d_ws;
  int* count = ws_i;          // [0]
  int* m_src = ws_i + 16;
  int* m_trg = m_src + CAP;
  int* m_bin = m_trg + CAP;

  zero_count<<<1, 1, 0, stream>>>(count);

  int blocks = (nE / 4 + 255) / 256;
  if (blocks < 1) blocks = 1;
  if (blocks > 2048) blocks = 2048;
  scan_edges<<<blocks, 256, 0, stream>>>(etrg, esrc, ebin, li_p, ld_p, nE,
                                         count, m_src, m_trg, m_bin);

  gat_head<<<1, 256, 0, stream>>>(nf, ms, li_p, ld_p, dist_p, Wproj, a_src, a_trg,
                                  Wms, demb_g, Wdist, Wskip, gbias, demb_h,
                                  W1, b1, W2, b2,
                                  count, m_src, m_trg, m_bin, (float*)d_out);
}

// Round 2
// 38.019 us; speedup vs baseline: 1.9231x; 1.9231x over previous
//
#include <hip/hip_runtime.h>
#include <hip/hip_bf16.h>
#include <math.h>

#define D_IN  128
#define NH    8
#define F_OUT 32
#define HID   256
#define D_EMB 64
#define FDIM  (HID + 2 * F_OUT + D_EMB)   // 384
#define CAP   128        // max matched edges (expected ~32 = Poisson(16)x2; 4x margin)
#define PRE_BLOCKS 9     // precompute task blocks fused into the scan kernel

// ---------------- ws layout (4-byte units) ----------------
// int  [0]                  count
// int  [16 .. 16+CAP)       m_src
// int  [16+CAP .. 16+2CAP)  m_trg
// int  [16+2CAP..16+3CAP)   m_bin
// float base FB = 512:
//   proj : FB            + e*256   (CAP*256)   per-edge Wproj@nf[src]
//   ssrc : after proj    + e*8+h   (CAP*8)
//   esc  : +CAP*8                  (CAP*8)
//   strg : +16                     s_trg for li/ld
//   sms  : +8                      Wms@ms
//   skip : +512                    nf[li/ld]@Wskip^T (t*256+r)
//   pre1 : +256                    W1[:,0:256]@ms + W1[:,320:384]@demb_h + b1

__device__ __forceinline__ float red32(float v) {
#pragma unroll
  for (int o = 16; o > 0; o >>= 1) v += __shfl_down(v, o, 32);
  return v;
}

__global__ __launch_bounds__(256) void scan_pre(
    const int* __restrict__ trg, const int* __restrict__ src,
    const int* __restrict__ bins, const int* __restrict__ li_p,
    const int* __restrict__ ld_p, const int* __restrict__ dist_p, int nE,
    const float* __restrict__ nf, const float* __restrict__ ms,
    const float* __restrict__ Wproj, const float* __restrict__ a_trg,
    const float* __restrict__ Wms, const float* __restrict__ Wskip,
    const float* __restrict__ W1, const float* __restrict__ b1,
    const float* __restrict__ demb_h,
    int* __restrict__ count, int* __restrict__ m_src,
    int* __restrict__ m_trg, int* __restrict__ m_bin,
    float* __restrict__ strg, float* __restrict__ sms,
    float* __restrict__ skipb, float* __restrict__ pre1) {
  const int b = blockIdx.x;
  const int tid = threadIdx.x;

  if (b < PRE_BLOCKS) {
    // ---- precompute tasks (independent of edge scan) ----
    __shared__ __align__(16) float s_nf[D_IN];
    const int task = b;
    if (task < 4) {  // proj-target -> strg (0,1) ; skip rows (2,3)
      const int t = task & 1;
      const int node = t ? ld_p[0] : li_p[0];
      if (tid < 32) ((float4*)s_nf)[tid] = ((const float4*)nf)[(size_t)node * 32 + tid];
      __syncthreads();
      const float* Wrow = (task < 2 ? Wproj : Wskip) + tid * D_IN;
      const float4* w4 = (const float4*)Wrow;
      const float4* x4 = (const float4*)s_nf;
      float acc = 0.f;
#pragma unroll
      for (int i = 0; i < 32; ++i) {
        float4 w = w4[i], x = x4[i];
        acc = fmaf(w.x, x.x, acc); acc = fmaf(w.y, x.y, acc);
        acc = fmaf(w.z, x.z, acc); acc = fmaf(w.w, x.w, acc);
      }
      if (task < 2) {
        int h = tid >> 5, f = tid & 31;
        float v = red32(acc * a_trg[h * F_OUT + f]);
        if (f == 0) strg[t * NH + h] = v;
      } else {
        skipb[t * 256 + tid] = acc;
      }
    } else if (task == 4) {  // sms[h] = Wms[h] . ms
      int h = tid >> 5, j = tid & 31;
      float v = 0.f;
      for (int k = j; k < HID; k += 32) v = fmaf(Wms[h * HID + k], ms[k], v);
      v = red32(v);
      if (j == 0) sms[h] = v;
    } else {  // pre1 rows, tasks 5..8 -> 64 rows each, 4 threads/row
      const int dist = dist_p[0];
      const int row = (task - 5) * 64 + (tid >> 2);
      const int l = tid & 3;
      const float* w = W1 + row * FDIM;
      float acc = 0.f;
      const float4* wm = (const float4*)(w + l * 64);
      const float4* mv = (const float4*)(ms + l * 64);
#pragma unroll
      for (int i = 0; i < 16; ++i) {
        float4 a = wm[i], x = mv[i];
        acc = fmaf(a.x, x.x, acc); acc = fmaf(a.y, x.y, acc);
        acc = fmaf(a.z, x.z, acc); acc = fmaf(a.w, x.w, acc);
      }
      const float* wd = w + HID + 2 * F_OUT + l * 16;
      const float* dv = demb_h + (size_t)dist * D_EMB + l * 16;
#pragma unroll
      for (int i = 0; i < 16; ++i) acc = fmaf(wd[i], dv[i], acc);
#pragma unroll
      for (int o = 2; o > 0; o >>= 1) acc += __shfl_down(acc, o, 4);
      if (l == 0) pre1[row] = acc + b1[row];
    }
    return;
  }

  // ---- edge scan ----
  const int li = li_p[0], ld = ld_p[0];
  const int gid = (b - PRE_BLOCKS) * 256 + tid;
  const int stride = (gridDim.x - PRE_BLOCKS) * 256;
  const int nE4 = nE >> 2;
  const int4* t4 = (const int4*)trg;
  for (int e4 = gid; e4 < nE4; e4 += stride) {
    int4 t = t4[e4];
    int ev[4] = {t.x, t.y, t.z, t.w};
#pragma unroll
    for (int k = 0; k < 4; ++k) {
      int tv = ev[k];
      if (tv == li || tv == ld) {
        int e = e4 * 4 + k;
        int pos = atomicAdd(count, 1);
        if (pos < CAP) { m_src[pos] = src[e]; m_trg[pos] = tv; m_bin[pos] = bins[e]; }
      }
    }
  }
  if (gid == 0) {
    for (int e = nE4 * 4; e < nE; ++e) {
      int tv = trg[e];
      if (tv == li || tv == ld) {
        int pos = atomicAdd(count, 1);
        if (pos < CAP) { m_src[pos] = src[e]; m_trg[pos] = tv; m_bin[pos] = bins[e]; }
      }
    }
  }
}

// one block per matched edge: proj[e] = Wproj @ nf[src_e]; ssrc[e,h]; esc[e,h]
__global__ __launch_bounds__(256) void edge_proj(
    const float* __restrict__ nf, const float* __restrict__ Wproj,
    const float* __restrict__ a_src, const float* __restrict__ demb_g,
    const float* __restrict__ Wdist,
    const int* __restrict__ count, const int* __restrict__ m_src,
    const int* __restrict__ m_bin,
    float* __restrict__ proj, float* __restrict__ ssrc, float* __restrict__ esc) {
  const int tid = threadIdx.x;
  int cnt = *count; if (cnt > CAP) cnt = CAP;
  __shared__ __align__(16) float s_nf[D_IN];
  for (int e = blockIdx.x; e < cnt; e += gridDim.x) {
    const int sv = m_src[e], bv = m_bin[e];
    __syncthreads();
    if (tid < 32) ((float4*)s_nf)[tid] = ((const float4*)nf)[(size_t)sv * 32 + tid];
    __syncthreads();
    const float4* w4 = (const float4*)(Wproj + tid * D_IN);
    const float4* x4 = (const float4*)s_nf;
    float acc = 0.f;
#pragma unroll
    for (int i = 0; i < 32; ++i) {
      float4 w = w4[i], x = x4[i];
      acc = fmaf(w.x, x.x, acc); acc = fmaf(w.y, x.y, acc);
      acc = fmaf(w.z, x.z, acc); acc = fmaf(w.w, x.w, acc);
    }
    proj[e * 256 + tid] = acc;
    const int h = tid >> 5, f = tid & 31;
    float vs = red32(acc * a_src[h * F_OUT + f]);
    float ev = red32(demb_g[(size_t)bv * D_EMB + f] * Wdist[h * D_EMB + f] +
                     demb_g[(size_t)bv * D_EMB + 32 + f] * Wdist[h * D_EMB + 32 + f]);
    if (f == 0) { ssrc[e * NH + h] = vs; esc[e * NH + h] = ev; }
  }
}

__global__ __launch_bounds__(256) void final_k(
    const int* __restrict__ li_p, const int* __restrict__ ld_p,
    const int* __restrict__ count, const int* __restrict__ m_trg,
    const float* __restrict__ proj, const float* __restrict__ ssrc,
    const float* __restrict__ esc, const float* __restrict__ strg,
    const float* __restrict__ sms, const float* __restrict__ skipb,
    const float* __restrict__ pre1, const float* __restrict__ gbias,
    const float* __restrict__ W1, const float* __restrict__ W2,
    const float* __restrict__ b2, float* __restrict__ out) {
  __shared__ float s_p[CAP * NH];
  __shared__ float s_den[16];
  __shared__ float s_out[2 * 256];
  __shared__ __align__(16) float s_emb[2 * F_OUT];
  __shared__ float s_red[4];
  const int tid = threadIdx.x;
  const int li = li_p[0], ld = ld_p[0];
  int cnt = *count; if (cnt > CAP) cnt = CAP;

  // exp(leaky_relu(score)); reference's global max cancels in exp_s/denom
  for (int idx = tid; idx < cnt * NH; idx += 256) {
    int e = idx >> 3, h = idx & 7;
    int t = (m_trg[e] == li) ? 0 : 1;
    float sc = ssrc[idx] + strg[t * NH + h] + sms[h] + esc[idx];
    sc = sc > 0.f ? sc : 0.2f * sc;
    s_p[idx] = expf(sc);
  }
  __syncthreads();
  if (tid < 16) {
    int t = tid >> 3, h = tid & 7;
    int tv = t ? ld : li;
    float d = 0.f;
    for (int e = 0; e < cnt; ++e) if (m_trg[e] == tv) d += s_p[e * NH + h];
    s_den[tid] = d + 1e-16f;
  }
  __syncthreads();
  // out[t,r] = (sum_e attn * proj[e,r]) + skip[t,r]
  for (int idx = tid; idx < 512; idx += 256) {
    int t = idx >> 8, r = idx & 255, h = r >> 5;
    int tv = t ? ld : li;
    float acc = 0.f;
    for (int e = 0; e < cnt; ++e)
      if (m_trg[e] == tv) acc = fmaf(s_p[e * NH + h], proj[e * 256 + r], acc);
    s_out[idx] = acc / s_den[t * NH + h] + skipb[idx];
  }
  __syncthreads();
  if (tid < 2 * F_OUT) {  // head-mean + bias + ELU
    int t = tid >> 5, f = tid & 31;
    float s = 0.f;
#pragma unroll
    for (int h = 0; h < NH; ++h) s += s_out[t * 256 + h * F_OUT + f];
    s = s * 0.125f + gbias[f];
    s_emb[tid] = s > 0.f ? s : expm1f(s);
  }
  __syncthreads();
  // h1 = relu(pre1 + W1[:,256:320] @ emb); out = W2 . h1 + b2
  float acc = pre1[tid];
  const float4* w4 = (const float4*)(W1 + tid * FDIM + HID);
  const float4* e4 = (const float4*)s_emb;
#pragma unroll
  for (int i = 0; i < 16; ++i) {
    float4 w = w4[i], x = e4[i];
    acc = fmaf(w.x, x.x, acc); acc = fmaf(w.y, x.y, acc);
    acc = fmaf(w.z, x.z, acc); acc = fmaf(w.w, x.w, acc);
  }
  acc = fmaxf(acc, 0.f);
  float c = W2[tid] * acc;
#pragma unroll
  for (int o = 32; o > 0; o >>= 1) c += __shfl_down(c, o, 64);
  if ((tid & 63) == 0) s_red[tid >> 6] = c;
  __syncthreads();
  if (tid == 0) out[0] = s_red[0] + s_red[1] + s_red[2] + s_red[3] + b2[0];
}

extern "C" void kernel_launch(void* const* d_in, const int* in_sizes, int n_in,
                              void* d_out, int out_size, void* d_ws, size_t ws_size,
                              hipStream_t stream) {
  const float* nf     = (const float*)d_in[0];
  const int*   esrc   = (const int*)d_in[1];
  const int*   etrg   = (const int*)d_in[2];
  const int*   ebin   = (const int*)d_in[3];
  const float* ms     = (const float*)d_in[4];
  const int*   li_p   = (const int*)d_in[5];
  const int*   ld_p   = (const int*)d_in[6];
  const int*   dist_p = (const int*)d_in[7];
  const float* Wproj  = (const float*)d_in[8];
  const float* a_src  = (const float*)d_in[9];
  const float* a_trg  = (const float*)d_in[10];
  const float* Wms    = (const float*)d_in[11];
  const float* demb_g = (const float*)d_in[12];
  const float* Wdist  = (const float*)d_in[13];
  const float* Wskip  = (const float*)d_in[14];
  const float* gbias  = (const float*)d_in[15];
  const float* demb_h = (const float*)d_in[16];
  const float* W1     = (const float*)d_in[17];
  const float* b1     = (const float*)d_in[18];
  const float* W2     = (const float*)d_in[19];
  const float* b2     = (const float*)d_in[20];
  const int nE = in_sizes[1];

  int* ws_i  = (int*)d_ws;
  int*   count = ws_i;
  int*   m_src = ws_i + 16;
  int*   m_trg = m_src + CAP;
  int*   m_bin = m_trg + CAP;
  float* fb    = (float*)d_ws + 512;
  float* proj  = fb;                     // CAP*256
  float* ssrc  = proj + CAP * 256;       // CAP*8
  float* esc   = ssrc + CAP * NH;        // CAP*8
  float* strg  = esc + CAP * NH;         // 16
  float* sms   = strg + 16;              // 8
  float* skipb = sms + 8;                // 512
  float* pre1  = skipb + 512;            // 256

  hipMemsetAsync(count, 0, sizeof(int), stream);

  int scan_blocks = (nE / 4 + 255) / 256;
  if (scan_blocks < 1) scan_blocks = 1;
  if (scan_blocks > 2048) scan_blocks = 2048;
  scan_pre<<<scan_blocks + PRE_BLOCKS, 256, 0, stream>>>(
      etrg, esrc, ebin, li_p, ld_p, dist_p, nE,
      nf, ms, Wproj, a_trg, Wms, Wskip, W1, b1, demb_h,
      count, m_src, m_trg, m_bin, strg, sms, skipb, pre1);

  edge_proj<<<64, 256, 0, stream>>>(nf, Wproj, a_src, demb_g, Wdist,
                                    count, m_src, m_bin, proj, ssrc, esc);

  final_k<<<1, 256, 0, stream>>>(li_p, ld_p, count, m_trg, proj, ssrc, esc,
                                 strg, sms, skipb, pre1, gbias, W1, W2, b2,
                                 (float*)d_out);
}